// Round 11
// baseline (143.527 us; speedup 1.0000x reference)
//
#include <hip/hip_runtime.h>

typedef _Float16 half8  __attribute__((ext_vector_type(8)));
typedef __fp16   fp16x2 __attribute__((ext_vector_type(2)));   // cvt_pkrtz native type
typedef float    floatx4 __attribute__((ext_vector_type(4)));

#define IMG_H 64
#define IMG_W 64
#define TH 16
#define TW 32
#define INW 40            // staged cols: tx0-4 .. tx0+35
#define H1W 34            // h1 cols: tx0-1 .. tx0+32
#define NH1 612           // 18*34 real h1 pixels
#define NPX 624           // padded plane size in px
#define CP 912            // f16 elems per copy; stride 456 dwords ≡ 8 mod 32 banks

__device__ __forceinline__ unsigned pk2u(float a, float b) {
    fp16x2 h = __builtin_amdgcn_cvt_pkrtz(a, b);
    return __builtin_bit_cast(unsigned, h);
}

__global__ __launch_bounds__(256, 8) void pixelcnn_mfma8(
    const float* __restrict__ x,
    const float* __restrict__ w1, const float* __restrict__ b1,
    const float* __restrict__ w2, const float* __restrict__ b2,
    const float* __restrict__ w3, const float* __restrict__ b3,
    float* __restrict__ out)
{
    // LDS: 7296 + 1024 + 1536 + 196 + 9984 = 20036 B -> 8 blocks/CU (8*20480 = 160 KiB)
    __shared__ __align__(16) _Float16      s16[4 * CP];     // input tile f16, 4 shifted copies
    __shared__ __align__(16) _Float16      s_w1t[16 * 32];  // [ch][k] f16, k=(kr=q)*8+(kc=j)
    __shared__ __align__(16) unsigned char s_w2t8[16 * 96]; // [ch][k] fp8 e4m3, k=tap*16+ic
    __shared__ __align__(16) float         s_b1[16], s_b2[16], s_w3[16];
    __shared__ float                       s_b3;
    __shared__ __align__(16) unsigned      s_h1[2 * NPX * 2]; // fp8 h1: [c2][px][8ch] 8B/px/plane

    const int t    = threadIdx.x;
    const int lane = t & 63;
    const int wave = t >> 6;
    const int n    = lane & 15;   // MFMA: weight-row ch field & B-col pixel field
    const int quad = lane >> 4;   // MFMA k-slice group / D-row quad
    const int img  = blockIdx.y;
    const int btile = blockIdx.x;
    const int ty0 = (btile >> 1) * TH;
    const int tx0 = (btile & 1) * TW;

    const float* xim = x + img * (IMG_H * IMG_W);

    // ------- Phase 0: stage input as f16 x4 shifted copies + weights -------
    if (t < 210) {
        int r = t / 10, c4 = (t - r * 10) * 4;
        int gy = ty0 - 4 + r;
        int gx0 = tx0 - 4 + c4;                 // multiple of 4
        float4 v  = {0.f, 0.f, 0.f, 0.f};
        float4 v2 = {0.f, 0.f, 0.f, 0.f};
        if ((unsigned)gy < IMG_H) {
            const float* rp = xim + gy * IMG_W;
            if ((unsigned)gx0 < IMG_W)       v  = *(const float4*)(rp + gx0);
            if ((unsigned)(gx0 + 4) < IMG_W) v2 = *(const float4*)(rp + gx0 + 4);
        }
        unsigned a0 = pk2u(v.x,  v.y),  a1 = pk2u(v.z,  v.w);
        unsigned a2 = pk2u(v2.x, v2.y), a3 = pk2u(v2.z, v2.w);
        unsigned m10 = (a0 >> 16) | (a1 << 16);   // elems 1,2
        unsigned m21 = (a1 >> 16) | (a2 << 16);   // elems 3,4
        unsigned m32 = (a2 >> 16) | (a3 << 16);   // elems 5,6
        int lin = r * INW + c4;
        *(uint2*)&s16[0*CP + 0 + lin + 0] = uint2{a0,  a1 };  // cols c4..c4+3
        *(uint2*)&s16[1*CP + 3 + lin + 1] = uint2{m10, m21};  // cols c4+1..c4+4
        *(uint2*)&s16[2*CP + 2 + lin + 2] = uint2{a1,  a2 };  // cols c4+2..c4+5
        *(uint2*)&s16[3*CP + 1 + lin + 3] = uint2{m21, m32};  // cols c4+3..c4+6
    }
    // Zero the tail sliver each copy can read past staged content.
    if (t < 192) {
        int c = t / 48, e = t - c * 48;
        s16[c * CP + ((4 - c) & 3) + 840 + e] = (_Float16)0.f;
    }
    {
        int ch = t >> 4, l = t & 15;         // 256 threads = 16 ch x 16 lanes
        const float* w1c = w1 + ch * 49;
#pragma unroll
        for (int j2 = 0; j2 < 2; ++j2) {     // w1t: k = q*8+j <-> tap (kr=q, kc=j)
            int k = l + 16 * j2, q = k >> 3, jj = k & 7;
            float v = 0.f;
            if (q < 3)      { if (jj < 7) v = w1c[q * 7 + jj]; }
            else            { if (jj < 3) v = w1c[21 + jj];    }
            s_w1t[ch * 32 + k] = (_Float16)v;
        }
        const float* w2cl = w2 + (ch * 16 + l) * 9;   // w2t8: k = tap*16 + ic(=l), fp8 e4m3
#pragma unroll
        for (int j = 0; j < 6; ++j) {
            float v = (j < 5) ? w2cl[j] : 0.f;
            unsigned q8 = (unsigned)__builtin_amdgcn_cvt_pk_fp8_f32(v, 0.f, 0, false);
            s_w2t8[ch * 96 + j * 16 + l] = (unsigned char)(q8 & 0xff);
        }
    }
    if (t < 16) { s_b1[t] = b1[t]; s_b2[t] = b2[t]; s_w3[t] = w3[t]; }
    if (t == 16) s_b3 = b3[0];
    __syncthreads();

    // ------- Phase 1: L1 7x7 via f16 MFMA, row-tiled (lane geometry loop-invariant) -------
    // Col-blocks at x = {0,16,18}: overlap cols 18..31 written twice with identical
    // bytes (benign). Wave w handles rows py = w, w+4, ... < 18.
    {
        const half8 afrag = *(const half8*)&s_w1t[n * 32 + quad * 8];
        const floatx4 bias1 = ((const floatx4*)s_b1)[quad];
#pragma unroll
        for (int xb = 0; xb < 3; ++xb) {
            const int xbase = (xb == 0) ? 0 : ((xb == 1) ? 16 : 18);
            const int px = xbase + n;
            const int c = px & 3;
            // s16 elem index of this lane's fragment for row (py+quad), py = wave
            int rd = c * CP + ((4 - c) & 3) + (wave + quad) * INW + px;
            // s_h1 dword index for pixel p = py*H1W + px, py = wave
            int wd = (quad >> 1) * (NPX * 2) + (wave * H1W + px) * 2 + (quad & 1);
            const bool gxok = (unsigned)(tx0 - 1 + px) < IMG_W;
            for (int py = wave; py < 18; py += 4) {
                uint2 lo = *(const uint2*)&s16[rd];       // elems px..px+3 (8B aligned)
                uint2 hi = *(const uint2*)&s16[rd + 4];   // elems px+4..px+7
                uint4 bu; bu.x = lo.x; bu.y = lo.y; bu.z = hi.x; bu.w = hi.y;
                half8 b = __builtin_bit_cast(half8, bu);
                floatx4 acc = bias1;
                acc = __builtin_amdgcn_mfma_f32_16x16x32_f16(afrag, b, acc, 0, 0, 0);
                // D: row = ch = quad*4+r, col = px = n -> 4 ch as 4 fp8 bytes = one b32
                bool inimg = gxok & ((unsigned)(ty0 - 1 + py) < IMG_H);
                int d = __builtin_amdgcn_cvt_pk_fp8_f32(fmaxf(acc[0], 0.f), fmaxf(acc[1], 0.f), 0, false);
                d = __builtin_amdgcn_cvt_pk_fp8_f32(fmaxf(acc[2], 0.f), fmaxf(acc[3], 0.f), d, true);
                s_h1[wd] = inimg ? (unsigned)d : 0u;
                rd += 4 * INW;          // +4 rows in s16
                wd += 4 * H1W * 2;      // +4 rows of h1 px
            }
        }
    }
    __syncthreads();

    // ------- Phase 2: L2 3x3 via fp8 MFMA + fused relu/w3-dot/sigmoid/store -------
    {
        const long w2f0 = *(const long*)&s_w2t8[n * 96 +  0 + quad * 8];
        const long w2f1 = *(const long*)&s_w2t8[n * 96 + 32 + quad * 8];
        const long w2f2 = *(const long*)&s_w2t8[n * 96 + 64 + quad * 8];
        const floatx4 bias2 = ((const floatx4*)s_b2)[quad];
        const floatx4 w3q   = ((const floatx4*)s_w3)[quad];
        const float bias3 = s_b3;
        const int y0 = wave >> 1, x0 = (wave & 1) * 16;  // wave -> (row parity, col half)
        const int tqh = quad >> 1, plane = quad & 1;
        const int E0 = (y0 + 1) * H1W + x0 + n + 1;      // lane pixel in h1 coords (k=0)
        // taps: f0 -> {(-1,-1),(-1,0)}, f1 -> {(-1,1),(0,-1)}, f2 -> {(0,0), pad(A=0)}
        const char* h1b = (const char*)s_h1 + plane * (NPX * 8);
        const char* a0 = h1b + (E0 - 35 + tqh) * 8;
        const char* a1 = h1b + (E0 + (tqh ? -1 : -33)) * 8;
        const char* a2 = h1b + E0 * 8;                   // tqh=1 reads real px (zero A-side)
        float* optr = out + ((img * IMG_H) + ty0 + y0) * IMG_W + tx0 + x0 + n;

#pragma unroll
        for (int k = 0; k < 8; ++k) {                    // y = y0 + 2k; dE=68 px -> 544 B imm
            floatx4 acc = bias2;
            acc = __builtin_amdgcn_mfma_f32_16x16x32_fp8_fp8(w2f0, *(const long*)(a0 + k * 544), acc, 0, 0, 0);
            acc = __builtin_amdgcn_mfma_f32_16x16x32_fp8_fp8(w2f1, *(const long*)(a1 + k * 544), acc, 0, 0, 0);
            acc = __builtin_amdgcn_mfma_f32_16x16x32_fp8_fp8(w2f2, *(const long*)(a2 + k * 544), acc, 0, 0, 0);
            float s = fmaxf(acc[0], 0.f) * w3q[0];
            s = fmaf(fmaxf(acc[1], 0.f), w3q[1], s);
            s = fmaf(fmaxf(acc[2], 0.f), w3q[2], s);
            s = fmaf(fmaxf(acc[3], 0.f), w3q[3], s);
            s += __shfl_xor(s, 16);
            s += __shfl_xor(s, 32);
            if (lane < 16) {
                float r = 1.f / (1.f + __expf(-(s + bias3)));
                *(float*)((char*)optr + k * 512) = r;    // drow=2 -> 512 B imm
            }
        }
    }
}

extern "C" void kernel_launch(void* const* d_in, const int* in_sizes, int n_in,
                              void* d_out, int out_size, void* d_ws, size_t ws_size,
                              hipStream_t stream) {
    const float* x  = (const float*)d_in[0];
    const float* w1 = (const float*)d_in[1];
    const float* b1 = (const float*)d_in[2];
    const float* w2 = (const float*)d_in[3];
    const float* b2 = (const float*)d_in[4];
    const float* w3 = (const float*)d_in[5];
    const float* b3 = (const float*)d_in[6];
    float* out = (float*)d_out;

    dim3 grid(8, 1024);   // 2x4 tiles per image, 1024 images
    dim3 block(256);
    hipLaunchKernelGGL(pixelcnn_mfma8, grid, block, 0, stream,
                       x, w1, b1, w2, b2, w3, b3, out);
}

// Round 12
// 114.942 us; speedup vs baseline: 1.2487x; 1.2487x over previous
//
#include <hip/hip_runtime.h>

typedef _Float16 half8  __attribute__((ext_vector_type(8)));
typedef __fp16   fp16x2 __attribute__((ext_vector_type(2)));   // cvt_pkrtz native type
typedef float    floatx4 __attribute__((ext_vector_type(4)));

#define IMG_H 64
#define IMG_W 64
#define TH 16
#define TW 32
#define INW 40            // staged cols: tx0-4 .. tx0+35
#define H1W 34            // h1 cols: tx0-1 .. tx0+32
#define NH1 612           // 18*34 real h1 pixels
#define NPX 640           // padded plane (40 tiles x 16 px; p in [612,640) = write-only pad)
#define CP 912            // f16 elems per copy; stride 456 dwords ≡ 8 mod 32 banks

__device__ __forceinline__ unsigned pk2u(float a, float b) {
    fp16x2 h = __builtin_amdgcn_cvt_pkrtz(a, b);
    return __builtin_bit_cast(unsigned, h);
}

__global__ __launch_bounds__(256, 7) void pixelcnn_mfma9(
    const float* __restrict__ x,
    const float* __restrict__ w1, const float* __restrict__ b1,
    const float* __restrict__ w2, const float* __restrict__ b2,
    const float* __restrict__ w3, const float* __restrict__ b3,
    float* __restrict__ out)
{
    // LDS: 7296 + 1024 + 1536 + 196 + 10240 = 20292 B -> 7+ blocks/CU
    __shared__ __align__(16) _Float16      s16[4 * CP];     // input tile f16, 4 shifted copies
    __shared__ __align__(16) _Float16      s_w1t[16 * 32];  // [ch][k] f16, k=(kr=q)*8+(kc=j)
    __shared__ __align__(16) unsigned char s_w2t8[16 * 96]; // [ch][k] fp8 e4m3, k=tap*16+ic
    __shared__ __align__(16) float         s_b1[16], s_b2[16], s_w3[16];
    __shared__ float                       s_b3;
    __shared__ __align__(16) unsigned      s_h1[2 * NPX * 2]; // fp8 h1: [c2][px][8ch] 8B/px/plane

    const int t    = threadIdx.x;
    const int lane = t & 63;
    const int wave = t >> 6;
    const int n    = lane & 15;   // MFMA: weight-row ch field & B-col pixel field
    const int quad = lane >> 4;   // MFMA k-slice group / D-row quad
    const int img  = blockIdx.y;
    const int btile = blockIdx.x;
    const int ty0 = (btile >> 1) * TH;
    const int tx0 = (btile & 1) * TW;

    const float* xim = x + img * (IMG_H * IMG_W);

    // ------- Phase 0: stage input as f16 x4 shifted copies + weights -------
    if (t < 210) {
        int r = t / 10, c4 = (t - r * 10) * 4;
        int gy = ty0 - 4 + r;
        int gx0 = tx0 - 4 + c4;                 // multiple of 4
        float4 v  = {0.f, 0.f, 0.f, 0.f};
        float4 v2 = {0.f, 0.f, 0.f, 0.f};
        if ((unsigned)gy < IMG_H) {
            const float* rp = xim + gy * IMG_W;
            if ((unsigned)gx0 < IMG_W)       v  = *(const float4*)(rp + gx0);
            if ((unsigned)(gx0 + 4) < IMG_W) v2 = *(const float4*)(rp + gx0 + 4);
        }
        unsigned a0 = pk2u(v.x,  v.y),  a1 = pk2u(v.z,  v.w);
        unsigned a2 = pk2u(v2.x, v2.y), a3 = pk2u(v2.z, v2.w);
        unsigned m10 = (a0 >> 16) | (a1 << 16);   // elems 1,2
        unsigned m21 = (a1 >> 16) | (a2 << 16);   // elems 3,4
        unsigned m32 = (a2 >> 16) | (a3 << 16);   // elems 5,6
        int lin = r * INW + c4;
        *(uint2*)&s16[0*CP + 0 + lin + 0] = uint2{a0,  a1 };  // cols c4..c4+3
        *(uint2*)&s16[1*CP + 3 + lin + 1] = uint2{m10, m21};  // cols c4+1..c4+4
        *(uint2*)&s16[2*CP + 2 + lin + 2] = uint2{a1,  a2 };  // cols c4+2..c4+5
        *(uint2*)&s16[3*CP + 1 + lin + 3] = uint2{m21, m32};  // cols c4+3..c4+6
    }
    // Zero the tail sliver each copy can read past staged content (rel. elems
    // 840..887 cover all real and dummy fragment over-reads).
    if (t < 192) {
        int c = t / 48, e = t - c * 48;
        s16[c * CP + ((4 - c) & 3) + 840 + e] = (_Float16)0.f;
    }
    {
        int ch = t >> 4, l = t & 15;         // 256 threads = 16 ch x 16 lanes
        const float* w1c = w1 + ch * 49;
#pragma unroll
        for (int j2 = 0; j2 < 2; ++j2) {     // w1t: k = q*8+j <-> tap (kr=q, kc=j)
            int k = l + 16 * j2, q = k >> 3, jj = k & 7;
            float v = 0.f;
            if (q < 3)      { if (jj < 7) v = w1c[q * 7 + jj]; }
            else            { if (jj < 3) v = w1c[21 + jj];    }
            s_w1t[ch * 32 + k] = (_Float16)v;
        }
        const float* w2cl = w2 + (ch * 16 + l) * 9;   // w2t8: k = tap*16 + ic(=l), fp8 e4m3
#pragma unroll
        for (int j = 0; j < 6; ++j) {
            float v = (j < 5) ? w2cl[j] : 0.f;
            unsigned q8 = (unsigned)__builtin_amdgcn_cvt_pk_fp8_f32(v, 0.f, 0, false);
            s_w2t8[ch * 96 + j * 16 + l] = (unsigned char)(q8 & 0xff);
        }
    }
    if (t < 16) { s_b1[t] = b1[t]; s_b2[t] = b2[t]; s_w3[t] = w3[t]; }
    if (t == 16) s_b3 = b3[0];
    __syncthreads();

    // ------- Phase 1: L1 7x7 via f16 MFMA; uniform 10-trip loop, fully unrolled -------
    {
        const half8 afrag = *(const half8*)&s_w1t[n * 32 + quad * 8];
        const floatx4 bias1 = ((const floatx4*)s_b1)[quad];
        int p  = wave * 16 + n;
        int py = p / H1W, px = p - py * H1W;
        int lin1 = (py + quad) * INW + px;    // lane reads row py+quad, cols px..px+7
        int gy = ty0 - 1 + py;
        int gx = tx0 - 1 + px;
        unsigned wd = (unsigned)((quad >> 1) * (NPX * 2) + p * 2 + (quad & 1)); // dword idx

#pragma unroll
        for (int i = 0; i < 10; ++i) {        // tiles wave, wave+4, ..., wave+36 (pad tiles dummy)
            int c = px & 3;
            const _Float16* ap = &s16[c * CP + ((4 - c) & 3) + lin1];
            uint2 lo = *(const uint2*)ap;         // elems px..px+3 (8B aligned)
            uint2 hi = *(const uint2*)(ap + 4);   // elems px+4..px+7
            uint4 bu; bu.x = lo.x; bu.y = lo.y; bu.z = hi.x; bu.w = hi.y;
            half8 b = __builtin_bit_cast(half8, bu);
            floatx4 acc = bias1;
            acc = __builtin_amdgcn_mfma_f32_16x16x32_f16(afrag, b, acc, 0, 0, 0);
            // D: row = ch = quad*4+r, col = px = n -> 4 ch as 4 fp8 bytes = one b32
            bool inimg = ((unsigned)gy < IMG_H) & ((unsigned)gx < IMG_W);
            int d = __builtin_amdgcn_cvt_pk_fp8_f32(fmaxf(acc[0], 0.f), fmaxf(acc[1], 0.f), 0, false);
            d = __builtin_amdgcn_cvt_pk_fp8_f32(fmaxf(acc[2], 0.f), fmaxf(acc[3], 0.f), d, true);
            s_h1[wd] = inimg ? (unsigned)d : 0u;
            // branchless advance by 64 pixels: py += 1 (+wrap), px += 30
            int px2 = px + 30;
            bool wrap = px2 >= H1W;
            px    = wrap ? px2 - H1W : px2;
            gy   += wrap ? 2 : 1;
            gx    = wrap ? gx - 4 : gx + 30;
            lin1 += wrap ? 76 : 70;
            wd   += 128;
        }
    }
    __syncthreads();

    // ------- Phase 2: L2 3x3 via fp8 MFMA + fused relu/w3-dot/sigmoid/store -------
    {
        const long w2f0 = *(const long*)&s_w2t8[n * 96 +  0 + quad * 8];
        const long w2f1 = *(const long*)&s_w2t8[n * 96 + 32 + quad * 8];
        const long w2f2 = *(const long*)&s_w2t8[n * 96 + 64 + quad * 8];
        const floatx4 bias2 = ((const floatx4*)s_b2)[quad];
        const floatx4 w3q   = ((const floatx4*)s_w3)[quad];
        const float bias3 = s_b3;
        const int y0 = wave >> 1, x0 = (wave & 1) * 16;  // wave -> (row parity, col half)
        const int tqh = quad >> 1, plane = quad & 1;
        const int E0 = (y0 + 1) * H1W + x0 + n + 1;      // lane pixel in h1 coords (k=0)
        // taps: f0 -> {(-1,-1),(-1,0)}, f1 -> {(-1,1),(0,-1)}, f2 -> {(0,0), pad(A=0)}
        const char* h1b = (const char*)s_h1 + plane * (NPX * 8);
        const char* a0 = h1b + (E0 - 35 + tqh) * 8;
        const char* a1 = h1b + (E0 + (tqh ? -1 : -33)) * 8;
        const char* a2 = h1b + E0 * 8;                   // tqh=1 reads real px (zero A-side)
        float* optr = out + ((img * IMG_H) + ty0 + y0) * IMG_W + tx0 + x0 + n;

#pragma unroll
        for (int k = 0; k < 8; ++k) {                    // y = y0 + 2k; dE=68 px -> 544 B imm
            floatx4 acc = bias2;
            acc = __builtin_amdgcn_mfma_f32_16x16x32_fp8_fp8(w2f0, *(const long*)(a0 + k * 544), acc, 0, 0, 0);
            acc = __builtin_amdgcn_mfma_f32_16x16x32_fp8_fp8(w2f1, *(const long*)(a1 + k * 544), acc, 0, 0, 0);
            acc = __builtin_amdgcn_mfma_f32_16x16x32_fp8_fp8(w2f2, *(const long*)(a2 + k * 544), acc, 0, 0, 0);
            float s = fmaxf(acc[0], 0.f) * w3q[0];
            s = fmaf(fmaxf(acc[1], 0.f), w3q[1], s);
            s = fmaf(fmaxf(acc[2], 0.f), w3q[2], s);
            s = fmaf(fmaxf(acc[3], 0.f), w3q[3], s);
            s += __shfl_xor(s, 16);
            s += __shfl_xor(s, 32);
            if (lane < 16) {
                float r = 1.f / (1.f + __expf(-(s + bias3)));
                *(float*)((char*)optr + k * 512) = r;    // drow=2 -> 512 B imm
            }
        }
    }
}

extern "C" void kernel_launch(void* const* d_in, const int* in_sizes, int n_in,
                              void* d_out, int out_size, void* d_ws, size_t ws_size,
                              hipStream_t stream) {
    const float* x  = (const float*)d_in[0];
    const float* w1 = (const float*)d_in[1];
    const float* b1 = (const float*)d_in[2];
    const float* w2 = (const float*)d_in[3];
    const float* b2 = (const float*)d_in[4];
    const float* w3 = (const float*)d_in[5];
    const float* b3 = (const float*)d_in[6];
    float* out = (float*)d_out;

    dim3 grid(8, 1024);   // 2x4 tiles per image, 1024 images
    dim3 block(256);
    hipLaunchKernelGGL(pixelcnn_mfma9, grid, block, 0, stream,
                       x, w1, b1, w2, b2, w3, b3, out);
}